// Round 2
// baseline (2456.268 us; speedup 1.0000x reference)
//
#include <hip/hip_runtime.h>
#include <cmath>
#include <cstdint>
#include <cstddef>

namespace {
constexpr int kB = 4;
constexpr int kS = 2048;
constexpr int kD = 768;
constexpr int kH = 12;
constexpr int kHD = 64;
constexpr int k3D = 3 * kD;   // 2304
constexpr float kNeg = -1000000000.0f;
}

// Faithful fp32 masking affine: s = a + NEG*(1-a), no fma contraction so the
// rounding sequence matches numpy's elementwise ops. (Identical to round-1.)
__device__ __forceinline__ float mask_affine(float a) {
#pragma clang fp contract(off)
    const float u = 1.0f - a;
    return a + kNeg * u;
}

// ---------------------------------------------------------------------------
// fp32 tiled GEMM with bias, register-prefetch pipelined (T14 pattern).
// Accumulation order per output element is k-ascending fmaf — bit-identical
// to the round-1 kernel regardless of BK/tile params.
// ---------------------------------------------------------------------------
template <int BM, int BN, int BK, int TM, int TN>
__global__ __launch_bounds__(256)
void gemm_bias_kernel(const float* __restrict__ A, const float* __restrict__ Bm,
                      const float* __restrict__ bias, float* __restrict__ C,
                      int M, int N, int K)
{
    static_assert(BM * BN / (TM * TN) == 256, "256 threads");
    constexpr int AF4 = BM * BK / 1024;   // float4 loads per thread (A tile)
    constexpr int BF4 = BK * BN / 1024;   // float4 loads per thread (B tile)
    __shared__ float As[BK][BM + 4];      // transposed A tile, 16B-aligned rows
    __shared__ float Bs[BK][BN + 4];

    const int tid = threadIdx.x;
    constexpr int TX = BN / TN;
    const int tx = tid % TX;
    const int ty = tid / TX;
    const int m0 = blockIdx.y * BM;
    const int n0 = blockIdx.x * BN;

    float4 pa[AF4], pb[BF4];
    auto load_tiles = [&](int k0) {
#pragma unroll
        for (int it = 0; it < AF4; ++it) {
            const int e = (tid + it * 256) * 4;
            const int row = e / BK, col = e % BK;
            pa[it] = *reinterpret_cast<const float4*>(
                &A[(size_t)(m0 + row) * K + (k0 + col)]);
        }
#pragma unroll
        for (int it = 0; it < BF4; ++it) {
            const int e = (tid + it * 256) * 4;
            const int row = e / BN, col = e % BN;
            pb[it] = *reinterpret_cast<const float4*>(
                &Bm[(size_t)(k0 + row) * N + (n0 + col)]);
        }
    };

    float acc[TM][TN];
#pragma unroll
    for (int i = 0; i < TM; ++i)
#pragma unroll
        for (int j = 0; j < TN; ++j) acc[i][j] = 0.0f;

    load_tiles(0);
    for (int k0 = 0; k0 < K; k0 += BK) {
        // commit prefetched regs to LDS
#pragma unroll
        for (int it = 0; it < AF4; ++it) {
            const int e = (tid + it * 256) * 4;
            const int row = e / BK, col = e % BK;
            As[col + 0][row] = pa[it].x; As[col + 1][row] = pa[it].y;
            As[col + 2][row] = pa[it].z; As[col + 3][row] = pa[it].w;
        }
#pragma unroll
        for (int it = 0; it < BF4; ++it) {
            const int e = (tid + it * 256) * 4;
            const int row = e / BN, col = e % BN;
            *reinterpret_cast<float4*>(&Bs[row][col]) = pb[it];
        }
        __syncthreads();
        if (k0 + BK < K) load_tiles(k0 + BK);   // overlaps with compute below
#pragma unroll
        for (int kk = 0; kk < BK; ++kk) {
            float a[TM], b[TN];
#pragma unroll
            for (int i = 0; i < TM; i += 4) {
                const float4 v = *reinterpret_cast<const float4*>(&As[kk][ty * TM + i]);
                a[i] = v.x; a[i + 1] = v.y; a[i + 2] = v.z; a[i + 3] = v.w;
            }
#pragma unroll
            for (int j = 0; j < TN; j += 4) {
                const float4 v = *reinterpret_cast<const float4*>(&Bs[kk][tx * TN + j]);
                b[j] = v.x; b[j + 1] = v.y; b[j + 2] = v.z; b[j + 3] = v.w;
            }
#pragma unroll
            for (int i = 0; i < TM; ++i)
#pragma unroll
                for (int j = 0; j < TN; ++j)
                    acc[i][j] = fmaf(a[i], b[j], acc[i][j]);
        }
        __syncthreads();
    }

#pragma unroll
    for (int i = 0; i < TM; ++i) {
        const int m = m0 + ty * TM + i;
#pragma unroll
        for (int j = 0; j < TN; ++j) {
            const int n = n0 + tx * TN + j;
            C[(size_t)m * N + n] = acc[i][j] + bias[n];
        }
    }
}

// ---------------------------------------------------------------------------
// V tile-suffix sums: vsuf[b][h][t][d] = sum_{k>=64t} V[b][k][h*64+d].
// Needed for the rare rows whose entire causal prefix scores <= -1e9 (the
// masked keys, score == -1e9 exactly, then dominate the tie-average).
// ---------------------------------------------------------------------------
__global__ __launch_bounds__(256)
void vsuf_kernel(const float* __restrict__ qkv, float* __restrict__ vsuf)
{
    const int h = blockIdx.x, b = blockIdx.y;
    const int lane = threadIdx.x & 63, wave = threadIdx.x >> 6;
    const float* vp = qkv + (size_t)b * kS * k3D + 2 * kD + h * kHD;
    __shared__ float ts[32][64];

    for (int i = 0; i < 8; ++i) {
        const int t = wave * 8 + i;
        float s = 0.0f;
        for (int k = 0; k < 64; ++k)
            s += vp[(size_t)(t * 64 + k) * k3D + lane];
        ts[t][lane] = s;
    }
    __syncthreads();
    if (wave == 0) {
        float s = 0.0f;
        float* out = vsuf + (size_t)(b * kH + h) * 32 * 64;
        for (int t = 31; t >= 0; --t) {
            s += ts[t][lane];
            out[t * 64 + lane] = s;
        }
    }
}

// ---------------------------------------------------------------------------
// Attention, lane = query. Each lane holds its query row (prescaled by 1/8)
// and its 64-dim V accumulator in registers; max/tie/count bookkeeping is
// per-lane register ops. K/V tiles staged in LDS, broadcast-read (uniform
// address => conflict-free). Score arithmetic is bit-identical to round 1:
// same exact 0.125 prescale, same d-ascending fmaf chain, same mask_affine.
// ---------------------------------------------------------------------------
__global__ __launch_bounds__(256)
void attn_select_kernel(const float* __restrict__ qkv,
                        const float* __restrict__ vsuf,
                        float* __restrict__ ctx)
{
    const int b = blockIdx.z, h = blockIdx.y;
    const int q0 = blockIdx.x * 256;
    const int tid = threadIdx.x;
    const int wave = tid >> 6, lane = tid & 63;
    const int qi = q0 + wave * 64 + lane;

    __shared__ float Ks[64 * 68];   // 64 keys x 64 dims, row stride 68
    __shared__ float Vs[64 * 68];

    const float* qp = qkv + (size_t)b * kS * k3D + h * kHD;
    const float* kp = qp + kD;
    const float* vp = qp + 2 * kD;

    // Q row into registers, exact power-of-two prescale (== dividing the dot)
    float4 qv[16];
#pragma unroll
    for (int d4 = 0; d4 < 16; ++d4) {
        float4 t = *reinterpret_cast<const float4*>(&qp[(size_t)qi * k3D + d4 * 4]);
        qv[d4] = {t.x * 0.125f, t.y * 0.125f, t.z * 0.125f, t.w * 0.125f};
    }

    float4 vs4[16];
#pragma unroll
    for (int d4 = 0; d4 < 16; ++d4) vs4[d4] = {0.f, 0.f, 0.f, 0.f};
    float m = -INFINITY;
    int cnt = 0;

    const int Tblk = q0 / 64 + 4;           // tiles staged by this block
    const int Twave = q0 / 64 + wave + 1;   // tiles this wave computes

    for (int t = 0; t < Tblk; ++t) {
        __syncthreads();
        // stage K and V tiles (4096 floats each), 4 float4 per thread each
#pragma unroll
        for (int it = 0; it < 4; ++it) {
            const int f4 = tid + it * 256;
            const int key = f4 >> 4, d4 = f4 & 15;
            const float4 kvv = *reinterpret_cast<const float4*>(
                &kp[(size_t)(t * 64 + key) * k3D + d4 * 4]);
            *reinterpret_cast<float4*>(&Ks[key * 68 + d4 * 4]) = kvv;
            const float4 vvv = *reinterpret_cast<const float4*>(
                &vp[(size_t)(t * 64 + key) * k3D + d4 * 4]);
            *reinterpret_cast<float4*>(&Vs[key * 68 + d4 * 4]) = vvv;
        }
        __syncthreads();
        if (t >= Twave) continue;           // wave-uniform; barrier at loop top

        const int kbase = t * 64;
        auto consider = [&](int kg, float dotv) {
            const float s = (kg > qi) ? kNeg : mask_affine(dotv);
            const bool upd = s > m;
            const bool tie = (s == m);
            if (__any(upd || tie)) {
                const float* vr = &Vs[(kg - kbase) * 68];
                const float keep = upd ? 0.0f : 1.0f;
                const float addw = (upd || tie) ? 1.0f : 0.0f;
#pragma unroll
                for (int d4 = 0; d4 < 16; ++d4) {
                    const float4 v = *reinterpret_cast<const float4*>(vr + d4 * 4);
                    vs4[d4].x = fmaf(vs4[d4].x, keep, v.x * addw);
                    vs4[d4].y = fmaf(vs4[d4].y, keep, v.y * addw);
                    vs4[d4].z = fmaf(vs4[d4].z, keep, v.z * addw);
                    vs4[d4].w = fmaf(vs4[d4].w, keep, v.w * addw);
                }
                cnt = upd ? 1 : (tie ? cnt + 1 : cnt);
                m = upd ? s : m;
            }
        };

        for (int kk = 0; kk < 64; kk += 4) {
            float a0 = 0.f, a1 = 0.f, a2 = 0.f, a3 = 0.f;
            const float* kr0 = &Ks[(kk + 0) * 68];
            const float* kr1 = &Ks[(kk + 1) * 68];
            const float* kr2 = &Ks[(kk + 2) * 68];
            const float* kr3 = &Ks[(kk + 3) * 68];
#pragma unroll
            for (int d4 = 0; d4 < 16; ++d4) {
                const float4 q = qv[d4];
                const float4 kA = *reinterpret_cast<const float4*>(kr0 + d4 * 4);
                const float4 kB = *reinterpret_cast<const float4*>(kr1 + d4 * 4);
                const float4 kC = *reinterpret_cast<const float4*>(kr2 + d4 * 4);
                const float4 kE = *reinterpret_cast<const float4*>(kr3 + d4 * 4);
                a0 = fmaf(q.x, kA.x, a0); a0 = fmaf(q.y, kA.y, a0);
                a0 = fmaf(q.z, kA.z, a0); a0 = fmaf(q.w, kA.w, a0);
                a1 = fmaf(q.x, kB.x, a1); a1 = fmaf(q.y, kB.y, a1);
                a1 = fmaf(q.z, kB.z, a1); a1 = fmaf(q.w, kB.w, a1);
                a2 = fmaf(q.x, kC.x, a2); a2 = fmaf(q.y, kC.y, a2);
                a2 = fmaf(q.z, kC.z, a2); a2 = fmaf(q.w, kC.w, a2);
                a3 = fmaf(q.x, kE.x, a3); a3 = fmaf(q.y, kE.y, a3);
                a3 = fmaf(q.z, kE.z, a3); a3 = fmaf(q.w, kE.w, a3);
            }
            consider(kbase + kk + 0, a0);
            consider(kbase + kk + 1, a1);
            consider(kbase + kk + 2, a2);
            consider(kbase + kk + 3, a3);
        }
    }

    // tail: keys [Twave*64, S) are masked (score == -1e9 exactly) for every
    // query in this wave; relevant only when the running max <= -1e9.
    const int kend = Twave * 64;
    if (kend < kS) {
        const bool lt = (m < kNeg);
        const bool eq = (m == kNeg);
        if (__any(lt || eq)) {
            const float* sp = vsuf + ((size_t)(b * kH + h) * 32 + (kend >> 6)) * 64;
            const float keep = lt ? 0.0f : 1.0f;
            const float addw = (lt || eq) ? 1.0f : 0.0f;
#pragma unroll
            for (int d4 = 0; d4 < 16; ++d4) {
                const float4 v = *reinterpret_cast<const float4*>(sp + d4 * 4);
                vs4[d4].x = fmaf(vs4[d4].x, keep, v.x * addw);
                vs4[d4].y = fmaf(vs4[d4].y, keep, v.y * addw);
                vs4[d4].z = fmaf(vs4[d4].z, keep, v.z * addw);
                vs4[d4].w = fmaf(vs4[d4].w, keep, v.w * addw);
            }
            const int extra = kS - kend;
            cnt = lt ? extra : (eq ? cnt + extra : cnt);
        }
    }

    float* op = ctx + ((size_t)b * kS + qi) * kD + h * kHD;
    const float fc = (float)cnt;
#pragma unroll
    for (int d4 = 0; d4 < 16; ++d4) {
        const float4 r = {vs4[d4].x / fc, vs4[d4].y / fc,
                          vs4[d4].z / fc, vs4[d4].w / fc};
        *reinterpret_cast<float4*>(op + d4 * 4) = r;
    }
}

// ---------------------------------------------------------------------------
extern "C" void kernel_launch(void* const* d_in, const int* in_sizes, int n_in,
                              void* d_out, int out_size, void* d_ws, size_t ws_size,
                              hipStream_t stream)
{
    const float* x     = (const float*)d_in[0];
    const float* W_qkv = (const float*)d_in[1];
    const float* b_qkv = (const float*)d_in[2];
    const float* W_o   = (const float*)d_in[3];
    const float* b_o   = (const float*)d_in[4];
    float* out = (float*)d_out;

    // workspace carve: qkv [8192][2304] (75.5 MB) + ctx [8192][768] (25 MB).
    // vsuf (393 KB) lives in d_out scratch space: fully written by vsuf_kernel,
    // consumed by attn, then d_out is fully overwritten by the final GEMM.
    float* qkv  = (float*)d_ws;
    float* ctx  = qkv + (size_t)kB * kS * k3D;
    float* vsuf = out;

    // 1) qkv = x @ W_qkv + b_qkv      (M=8192, N=2304, K=768)
    {
        dim3 grid(k3D / 128, (kB * kS) / 128);
        gemm_bias_kernel<128, 128, 32, 8, 8><<<grid, 256, 0, stream>>>(
            x, W_qkv, b_qkv, qkv, kB * kS, k3D, kD);
    }
    // 1b) V tile-suffix sums for the all-masked-row tail
    {
        dim3 grid(kH, kB);
        vsuf_kernel<<<grid, 256, 0, stream>>>(qkv, vsuf);
    }
    // 2) attention (exact tie-averaged argmax == faithful fp32 softmax here)
    {
        dim3 grid(kS / 256, kH, kB);
        attn_select_kernel<<<grid, 256, 0, stream>>>(qkv, vsuf, ctx);
    }
    // 3) out = ctx @ W_o + b_o        (M=8192, N=768, K=768)
    {
        dim3 grid(kD / 128, (kB * kS) / 64);
        gemm_bias_kernel<64, 128, 32, 4, 8><<<grid, 256, 0, stream>>>(
            ctx, W_o, b_o, out, kB * kS, kD, kD);
    }
}